// Round 2
// baseline (996.648 us; speedup 1.0000x reference)
//
#include <hip/hip_runtime.h>

namespace {

constexpr int T_LEN = 2048;
constexpr int B_TOT = 2048;
constexpr int H1 = 36;
constexpr int NB = 16;      // batches per block = MFMA N
constexpr int BLOCK = 256;  // 3 A-waves (3 M-tiles each) + 1 L2 wave
constexpr int RS = 72;      // h row stride in halves: 144B = 36 dwords == 4 (mod 32)

typedef _Float16 f16x8 __attribute__((ext_vector_type(8)));
typedef _Float16 h16x2 __attribute__((ext_vector_type(2)));
typedef float f32x4 __attribute__((ext_vector_type(4)));

__device__ __forceinline__ float fdot2(float wb, float hb, float acc) {
#if __has_builtin(__builtin_amdgcn_fdot2)
  return __builtin_amdgcn_fdot2(__builtin_bit_cast(h16x2, wb),
                                __builtin_bit_cast(h16x2, hb), acc, false);
#else
  float d;
  asm("v_dot2_f32_f16 %0, %1, %2, %3" : "=v"(d) : "v"(wb), "v"(hb), "0"(acc));
  return d;
#endif
}
__device__ __forceinline__ float pack2h(float a, float b) {
  h16x2 t = {(_Float16)a, (_Float16)b};
  return __builtin_bit_cast(float, t);
}
// Quad-broadcast via DPP quad_perm (VALU, off the LDS pipe).
template <int CTRL>
__device__ __forceinline__ float qb(float v) {
  return __builtin_bit_cast(
      float, __builtin_amdgcn_update_dpp(0, __builtin_bit_cast(int, v), CTRL,
                                         0xf, 0xf, true));
}
// Packed fp16 relu: max(x, 0) on both halves of a dword. Lets the L2 wave
// relu the raw h row itself so A-waves write ONE plane, not two.
__device__ __forceinline__ float pkrelu(float v) {
  float r;
  asm("v_pk_max_f16 %0, %1, %2" : "=v"(r) : "v"(v), "v"(0.f));
  return r;
}
__device__ __forceinline__ float fexp2(float x) { return __builtin_amdgcn_exp2f(x); }
__device__ __forceinline__ float frcp(float x) { return __builtin_amdgcn_rcpf(x); }
__device__ __forceinline__ float sigm(float x) { return frcp(1.f + fexp2(x * -1.44269504f)); }
__device__ __forceinline__ float tanh_fast(float x) {
  return fmaf(2.f, frcp(1.f + fexp2(x * -2.88539008f)), -1.f);  // 2*sigm(2x)-1
}

// Barrier WITHOUT the vmcnt(0)/expcnt(0) drain __syncthreads() emits: cross-wave
// data flows only through LDS, so lgkmcnt(0) (this wave's ds reads+writes retired)
// before s_barrier is sufficient. Keeps x prefetch / out stores in flight.
__device__ __forceinline__ void step_sync() {
  asm volatile("s_waitcnt lgkmcnt(0)" ::: "memory");
  __builtin_amdgcn_s_barrier();
  __builtin_amdgcn_sched_barrier(0);   // don't hoist next step's ds_reads above
  asm volatile("" ::: "memory");
}

__global__ __launch_bounds__(BLOCK) void lstm2_kernel(
    const float* __restrict__ x, const float* __restrict__ Wih1,
    const float* __restrict__ Whh1, const float* __restrict__ bih1,
    const float* __restrict__ bhh1, const float* __restrict__ Wih2,
    const float* __restrict__ Whh2, const float* __restrict__ bih2,
    const float* __restrict__ bhh2, float* __restrict__ out)
{
  // lds[buf][batch n][k=unit] = h1 as fp16. halves 36..71 stay zero forever
  // (zero-pad for the k>=36 region of the second MFMA's B operand).
  __shared__ __align__(16) _Float16 lds[2][NB][RS];

  const int tid = threadIdx.x;
  const int wid = tid >> 6;
  const int lane = tid & 63;
  const int g0 = blockIdx.x * NB;
  const bool isA = wid < 3;

  for (int i = tid; i < 2 * NB * RS; i += BLOCK)
    ((_Float16*)lds)[i] = (_Float16)0.f;  // h_{-1}=0 and zero-pad k>=36
  __syncthreads();

  // ---- A-wave wid=0..2: 12 units each (3 M-tiles of 16 rows), all 4 gates,
  //      16 batches. Key change vs prev round: ONE wave reuses its B0/B1 LDS
  //      read across 3 MFMA pairs -> 6 ds_read_b128/step/CU instead of 18.
  const int m = lane & 15;   // A: row index / B,C: batch col
  const int q = lane >> 4;   // A,B: k-group / C: row group (uloc)
  f16x8 A0[3] = {}, A1[3] = {};
  float wxc[3][4] = {}, bxc[3][4] = {};
  float c1v[3] = {0.f, 0.f, 0.f};
  const float* xc = nullptr;
  int ku0 = 0;
  if (isA) {
    ku0 = wid * 12 + q * 3;  // first of this lane's 3 contiguous units
#pragma unroll
    for (int t = 0; t < 3; ++t) {
      // A[mrow=m][k]: uloc=m>>2, g=m&3 -> unit u = wid*12 + uloc*3 + t
      const int uA = wid * 12 + (m >> 2) * 3 + t;
      const int ra = (m & 3) * H1 + uA;
#pragma unroll
      for (int j = 0; j < 8; ++j) {
        A0[t][j] = (_Float16)Whh1[ra * H1 + q * 8 + j];  // k = q*8+j < 32
        const int k1 = 32 + q * 8 + j;
        A1[t][j] = (k1 < H1) ? (_Float16)Whh1[ra * H1 + k1] : (_Float16)0.f;
      }
      // C rows held by this lane: mrow = q*4+r -> unit wid*12+q*3+t, gate r
#pragma unroll
      for (int r = 0; r < 4; ++r) {
        const int rc = r * H1 + (wid * 12 + q * 3 + t);
        wxc[t][r] = Wih1[rc];
        bxc[t][r] = bih1[rc] + bhh1[rc];
      }
    }
    xc = x + (size_t)(g0 + m) * T_LEN;
  }

  // ---- L2 wave (wid==3): lane = batch*4 + gate ----
  const int lb = lane >> 2, lg = lane & 3;
  float w2[18];
  float whg = 0.f, b2 = 0.f, c2 = 0.f, h2 = 0.f;
  float* outp = nullptr;
#pragma unroll
  for (int k = 0; k < 18; ++k) w2[k] = 0.f;
  if (!isA) {
    const float* wr = Wih2 + lg * H1;
#pragma unroll
    for (int k = 0; k < 18; ++k) w2[k] = pack2h(wr[2 * k], wr[2 * k + 1]);
    whg = Whh2[lg];
    b2 = bih2[lg] + bhh2[lg];
    outp = out + (size_t)(g0 + lb) * T_LEN;
  }

  float4 qx = make_float4(0.f, 0.f, 0.f, 0.f);
  if (isA) qx = *(const float4*)xc;  // x[0..3]
  float4 ov = make_float4(0.f, 0.f, 0.f, 0.f);

  // Step s reads buf[(s+1)&1], writes buf[s&1]; one barrier/step orders the
  // cross-wave handoff (all reads of a buffer precede the barrier before the
  // step that overwrites it).
  auto step = [&](int i, float xv, int s) {
    const int ib = (s + 1) & 1;  // holds h_{i-1}
    const int wb = s & 1;
    if (isA) {
      const f16x8 B0 = *(const f16x8*)&lds[ib][m][q * 8];        // k=q*8..+7
      const f16x8 B1 = *(const f16x8*)&lds[ib][m][32 + q * 8];   // zero pad k>=36
      f32x4 cc[3];
#pragma unroll
      for (int t = 0; t < 3; ++t)
#pragma unroll
        for (int r = 0; r < 4; ++r) cc[t][r] = fmaf(xv, wxc[t][r], bxc[t][r]);
#pragma unroll
      for (int t = 0; t < 3; ++t)
        cc[t] = __builtin_amdgcn_mfma_f32_16x16x32_f16(A0[t], B0, cc[t], 0, 0, 0);
#pragma unroll
      for (int t = 0; t < 3; ++t)
        cc[t] = __builtin_amdgcn_mfma_f32_16x16x32_f16(A1[t], B1, cc[t], 0, 0, 0);
#pragma unroll
      for (int t = 0; t < 3; ++t) {
        const float I = sigm(cc[t][0]), F = sigm(cc[t][1]);
        const float G = tanh_fast(cc[t][2]), O = sigm(cc[t][3]);
        c1v[t] = fmaf(F, c1v[t], I * G);
        const float h = O * tanh_fast(c1v[t]);
        lds[wb][m][ku0 + t] = (_Float16)h;  // 3 contiguous halves per lane
      }
    } else if (i > 0) {
      const char* rp = (const char*)&lds[ib][lb][0];  // h_{i-1}, row lb
      const float4 r0 = *(const float4*)rp;
      const float4 r1 = *(const float4*)(rp + 16);
      const float4 r2 = *(const float4*)(rp + 32);
      const float4 r3 = *(const float4*)(rp + 48);
      const float2 r4 = *(const float2*)(rp + 64);
      const float f[18] = {
          pkrelu(r0.x), pkrelu(r0.y), pkrelu(r0.z), pkrelu(r0.w),
          pkrelu(r1.x), pkrelu(r1.y), pkrelu(r1.z), pkrelu(r1.w),
          pkrelu(r2.x), pkrelu(r2.y), pkrelu(r2.z), pkrelu(r2.w),
          pkrelu(r3.x), pkrelu(r3.y), pkrelu(r3.z), pkrelu(r3.w),
          pkrelu(r4.x), pkrelu(r4.y)};
      float aE = 0.f, aO = 0.f;  // two accs: halve the dot dep-chain
#pragma unroll
      for (int k = 0; k < 18; k += 2) aE = fdot2(w2[k], f[k], aE);
#pragma unroll
      for (int k = 1; k < 18; k += 2) aO = fdot2(w2[k], f[k], aO);
      const float pre = (aE + aO) + fmaf(h2, whg, b2);  // this lane's gate lg
      const float pI = qb<0x00>(pre);  // quad-broadcast lane 0 (i)
      const float pF = qb<0x55>(pre);  // lane 1 (f)
      const float pG = qb<0xAA>(pre);  // lane 2 (g)
      const float pO = qb<0xFF>(pre);  // lane 3 (o)
      c2 = fmaf(sigm(pF), c2, sigm(pI) * tanh_fast(pG));
      h2 = sigm(pO) * tanh_fast(c2);  // = out[i-1], replicated in quad
      if (s == 1) ov.x = h2;
      else if (s == 2) ov.y = h2;
      else if (s == 3) ov.z = h2;
      else {
        ov.w = h2;
        if (lg == 0) *(float4*)(outp + (i - 4)) = ov;  // out[i-4..i-1]
      }
    }
    step_sync();
  };

  for (int i0 = 0; i0 < T_LEN; i0 += 4) {
    float4 qn = qx;
    if (isA) {  // prefetch next x quad (clamped; tail value unused garbage-OK)
      const int tn = (i0 + 4 < T_LEN) ? (i0 + 4) : (T_LEN - 4);
      qn = *(const float4*)(xc + tn);
    }
    step(i0 + 0, qx.x, 0);
    step(i0 + 1, qx.y, 1);
    step(i0 + 2, qx.z, 2);
    step(i0 + 3, qx.w, 3);
    qx = qn;
  }
  // Final iter i=2048: A-waves compute a discarded h_2048; L2 emits out[2047]
  // and stores out[2044..2047].
  step(T_LEN, qx.x, 0);
}

}  // namespace

extern "C" void kernel_launch(void* const* d_in, const int* in_sizes, int n_in,
                              void* d_out, int out_size, void* d_ws, size_t ws_size,
                              hipStream_t stream) {
  const float* x    = (const float*)d_in[0];
  const float* Wih1 = (const float*)d_in[1];
  const float* Whh1 = (const float*)d_in[2];
  const float* bih1 = (const float*)d_in[3];
  const float* bhh1 = (const float*)d_in[4];
  const float* Wih2 = (const float*)d_in[5];
  const float* Whh2 = (const float*)d_in[6];
  const float* bih2 = (const float*)d_in[7];
  const float* bhh2 = (const float*)d_in[8];
  float* out = (float*)d_out;

  dim3 grid(B_TOT / NB);  // 128 blocks x 16 batches
  dim3 block(BLOCK);      // 3 MFMA waves + 1 L2 wave
  hipLaunchKernelGGL(lstm2_kernel, grid, block, 0, stream,
                     x, Wih1, Whh1, bih1, bhh1, Wih2, Whh2, bih2, bhh2, out);
}